// Round 12
// baseline (229.806 us; speedup 1.0000x reference)
//
#include <hip/hip_runtime.h>

// Problem constants (fixed shapes from reference)
#define NE    1024
#define CDIM  64
#define BDIM  16
#define HDIM  64
#define WDIM  64
#define NPOS  (BDIM*HDIM*WDIM)          // 65536 positions
#define ZTOT  (BDIM*CDIM*HDIM*WDIM)     // 4194304 elements

// d_out offsets (float elements), concat in reference return order
#define ZQ_OFF   0
#define LOSS_OFF 4194304
#define IDX_OFF  4194305
#define EMB_OFF  4259841
#define CS_OFF   4325377
#define EA_OFF   4326401

// monotone float->uint mapping: a<b  <=>  ordf(a)<ordf(b)
__device__ __forceinline__ unsigned ordf(float x) {
    unsigned b = __float_as_uint(x);
    return (b & 0x80000000u) ? ~b : (b | 0x80000000u);
}

__device__ __forceinline__ unsigned long long umax64(unsigned long long a,
                                                     unsigned long long b) {
    return a > b ? a : b;
}

// ---------------- K0: codebook row norms, pre-scaled by -0.5 ----------------
__global__ __launch_bounds__(256) void k_enorm(const float* __restrict__ emb,
                                               float* __restrict__ en2) {
    int wid  = (blockIdx.x * blockDim.x + threadIdx.x) >> 6;   // row 0..1023
    int lane = threadIdx.x & 63;
    if (wid >= NE) return;
    float v = emb[wid * CDIM + lane];
    float s = v * v;
    #pragma unroll
    for (int off = 32; off > 0; off >>= 1) s += __shfl_xor(s, off);
    if (lane == 0) en2[wid] = -0.5f * s;
}

// ---------------- K1: fused argmin GEMM (16x4 lane tile) + emit ----------------
// Grid: 512 blocks x 256 threads (4 waves). Block owns 128 positions
// (2 bh-rows). 8 chunks of 128 codes; wave q scans [ch*128+q*32, +32).
// Lane (lr,lc): 16 positions (lr*16..+15) x 4 codes (lc*4 within wave range).
// Registers: acc 64 + z-dbuf 32 + E-dbuf 8 + best/bid 32 + misc ~ 155
// <= 170 (launch_bounds(256,3)) -> NO spill/AGPR traffic (R11: 16x8 tile
// needed ~225, allocator kept 128 arch-VGPRs -> AGPR/scratch shuffling,
// VALU bloat + 23.8MB writes). Per c-step: 64 fma vs 1 ds_read_b128 ->
// VALU-bound; z from global (8-way lane-dup -> 8x64B/instr, L2-resident).
// Argmin key=(ord(m)<<32)|(1023-j) => max-m-then-min-j == first-argmin.
// Same ascending-c chain per (p,j) as R6/R11 -> identical indices.
__global__ __launch_bounds__(256, 3) void k_fused4(const float* __restrict__ z,
                                                   const float* __restrict__ emb,
                                                   const float* __restrict__ en2,
                                                   float* __restrict__ out,
                                                   float* __restrict__ lossacc) {
    __shared__ float Et[64 * 128];            // 32 KB [c][jl], jl in 0..127
    __shared__ float Nn[128];                 // -0.5||e||^2 for chunk
    __shared__ unsigned long long keyL[128];  // per-position argmin key
    __shared__ float lred[4];

    const int t    = threadIdx.x;
    const int lane = t & 63;
    const int q    = t >> 6;          // wave 0..3 (code sub-range in chunk)
    const int lr   = lane >> 3;       // 0..7 position-16-group
    const int lc   = lane & 7;        // 0..7 code quad selector
    const int blk  = blockIdx.x;      // 0..511

    if (t < 128) keyL[t] = 0ull;

    // lane's z base: 16 consecutive w at row bh = blk*2 + (lr>>2)
    const int bh_l = blk * 2 + (lr >> 2);
    const size_t zlb = (size_t)(bh_l >> 6) * (CDIM * HDIM * WDIM)
                     + (size_t)(bh_l & 63) * WDIM + (lr & 3) * 16;
    const float* __restrict__ zl = z + zlb;
    const int jlbase = q * 32 + lc * 4;       // code offset within chunk

    float acc[16][4];
    float best[16];
    int   bid[16];
    #pragma unroll
    for (int p = 0; p < 16; ++p) { best[p] = -3.4e38f; bid[p] = 0; }

    #define LOADZ(A0, A1, A2, A3, C) do { \
        A0 = *(const float4*)(zl + (size_t)(C) * (HDIM*WDIM)); \
        A1 = *(const float4*)(zl + (size_t)(C) * (HDIM*WDIM) + 4); \
        A2 = *(const float4*)(zl + (size_t)(C) * (HDIM*WDIM) + 8); \
        A3 = *(const float4*)(zl + (size_t)(C) * (HDIM*WDIM) + 12); } while (0)
    #define LOADE(B0, C) do { \
        B0 = *(const float4*)&Et[(C) * 128 + jlbase]; } while (0)
    #define FMA4(P, ZV, E0) \
        acc[P][0] = fmaf(ZV, E0.x, acc[P][0]); \
        acc[P][1] = fmaf(ZV, E0.y, acc[P][1]); \
        acc[P][2] = fmaf(ZV, E0.z, acc[P][2]); \
        acc[P][3] = fmaf(ZV, E0.w, acc[P][3]);
    #define COMP(Z0, Z1, Z2, Z3, E0) do { \
        FMA4(0,  Z0.x, E0) FMA4(1,  Z0.y, E0) \
        FMA4(2,  Z0.z, E0) FMA4(3,  Z0.w, E0) \
        FMA4(4,  Z1.x, E0) FMA4(5,  Z1.y, E0) \
        FMA4(6,  Z1.z, E0) FMA4(7,  Z1.w, E0) \
        FMA4(8,  Z2.x, E0) FMA4(9,  Z2.y, E0) \
        FMA4(10, Z2.z, E0) FMA4(11, Z2.w, E0) \
        FMA4(12, Z3.x, E0) FMA4(13, Z3.y, E0) \
        FMA4(14, Z3.z, E0) FMA4(15, Z3.w, E0) } while (0)

    #pragma unroll 1
    for (int ch = 0; ch < 8; ++ch) {
        __syncthreads();   // prior chunk's Et/Nn reads complete

        // ---- stage Et[c][jl] transposed + Nn ----
        // thread t: code row t>>1, channel half t&1 (32 channels, 8 float4)
        {
            const int row  = t >> 1;
            const int half = t & 1;
            const float4* src = (const float4*)(emb
                + (size_t)(ch * 128 + row) * CDIM + half * 32);
            #pragma unroll
            for (int k = 0; k < 8; ++k) {
                float4 v = src[k];
                const int c0 = half * 32 + k * 4;
                Et[(c0 + 0) * 128 + row] = v.x;
                Et[(c0 + 1) * 128 + row] = v.y;
                Et[(c0 + 2) * 128 + row] = v.z;
                Et[(c0 + 3) * 128 + row] = v.w;
            }
            if (t < 128) Nn[t] = en2[ch * 128 + t];
        }
        __syncthreads();

        #pragma unroll
        for (int p = 0; p < 16; ++p)
            #pragma unroll
            for (int j = 0; j < 4; ++j) acc[p][j] = 0.f;

        float4 zA0, zA1, zA2, zA3, zB0, zB1, zB2, zB3;
        float4 eA0, eB0;
        LOADZ(zA0, zA1, zA2, zA3, 0);
        LOADE(eA0, 0);
        #pragma unroll 1
        for (int c = 0; c < 64; c += 2) {
            LOADZ(zB0, zB1, zB2, zB3, c + 1);
            LOADE(eB0, c + 1);
            COMP(zA0, zA1, zA2, zA3, eA0);
            if (c + 2 < 64) {
                LOADZ(zA0, zA1, zA2, zA3, c + 2);
                LOADE(eA0, c + 2);
            }
            COMP(zB0, zB1, zB2, zB3, eB0);
        }

        // ---- fold argmin for this chunk ----
        float4 n0 = *(const float4*)&Nn[jlbase];
        const int jg0 = ch * 128 + jlbase;
        #pragma unroll
        for (int p = 0; p < 16; ++p) {
            #define TRY(J, NV) { float m = acc[p][J] + NV; \
                if (m > best[p]) { best[p] = m; bid[p] = jg0 + J; } }
            TRY(0, n0.x) TRY(1, n0.y) TRY(2, n0.z) TRY(3, n0.w)
            #undef TRY
        }
    }
    #undef LOADZ
    #undef LOADE
    #undef FMA4
    #undef COMP

    // ---- merge across the 8 lc-lanes, then across waves via LDS atomicMax ----
    #pragma unroll
    for (int p = 0; p < 16; ++p) {
        unsigned long long key =
            ((unsigned long long)ordf(best[p]) << 32) | (unsigned)(1023 - bid[p]);
        key = umax64(key, __shfl_xor(key, 1));
        key = umax64(key, __shfl_xor(key, 2));
        key = umax64(key, __shfl_xor(key, 4));
        if (lc == 0) atomicMax(&keyL[lr * 16 + p], key);
    }
    __syncthreads();

    // ---- emit: idx, z_q (straight-through), loss ----
    {
        const int pl   = t & 127;          // position in block
        const int half = t >> 7;           // c-half 0/1
        const int bh   = blk * 2 + (pl >> 6);
        const int w    = pl & 63;
        const size_t zb0 = (size_t)(bh >> 6) * (CDIM * HDIM * WDIM)
                         + (size_t)(bh & 63) * WDIM + w;
        const int bx = 1023 - (int)(unsigned)(keyL[pl] & 0xFFFFFFFFull);

        if (half == 0) out[IDX_OFF + blk * 128 + pl] = (float)bx;

        const float4* ev = (const float4*)(emb + (size_t)bx * CDIM);
        float lsum = 0.f;
        #pragma unroll
        for (int k4 = 0; k4 < 8; ++k4) {
            float4 e4 = ev[half * 8 + k4];
            #pragma unroll
            for (int k = 0; k < 4; ++k) {
                const int c = half * 32 + k4 * 4 + k;
                float zv = z[zb0 + (size_t)c * (HDIM * WDIM)];
                float evv = (k == 0) ? e4.x : (k == 1) ? e4.y
                          : (k == 2) ? e4.z : e4.w;
                float df = evv - zv;
                out[ZQ_OFF + zb0 + (size_t)c * (HDIM * WDIM)] = zv + df;
                lsum = fmaf(df, df, lsum);
            }
        }

        #pragma unroll
        for (int off = 32; off > 0; off >>= 1) lsum += __shfl_xor(lsum, off);
        if ((t & 63) == 0) lred[t >> 6] = lsum;
        __syncthreads();
        if (t == 0)
            atomicAdd(lossacc, (lred[0] + lred[1]) + (lred[2] + lred[3]));
    }
}

// ---------------- K1b: esum/counts partials, channel x position-slice ----------------
__global__ __launch_bounds__(1024) void k_scatter(const float* __restrict__ z,
                                                  const float* __restrict__ idxf,
                                                  float* __restrict__ epart,
                                                  float* __restrict__ cntp,
                                                  int nslice) {
    __shared__ float accJ[NE];
    __shared__ float cntJ[NE];

    const int t = threadIdx.x;
    const int c = blockIdx.x & 63;
    const int s = blockIdx.x >> 6;
    accJ[t] = 0.f;
    cntJ[t] = 0.f;
    __syncthreads();

    const bool do_cnt = (c == 0);
    const int per = NPOS / nslice;
    const int p0  = s * per;
    for (int k = 0; k < per; k += 1024) {
        const int p = p0 + k + t;
        const int j = (int)idxf[p];                    // exact for 0..1023
        const int b = p >> 12, hw = p & 4095;
        const float zv = z[(size_t)b * (CDIM * HDIM * WDIM) + c * (HDIM * WDIM) + hw];
        atomicAdd(&accJ[j], zv);                       // ds_add_f32
        if (do_cnt) atomicAdd(&cntJ[j], 1.0f);
    }
    __syncthreads();

    epart[(size_t)s * (NE * CDIM) + t * CDIM + c] = accJ[t];
    if (do_cnt) cntp[s * NE + t] = cntJ[t];
}

// ---------------- K2: cluster-size EMA + n-sum + loss ----------------
__global__ __launch_bounds__(1024) void k_cluster(const float* __restrict__ cs_in,
                                                  const float* __restrict__ cntp,
                                                  const float* __restrict__ lossacc,
                                                  float* __restrict__ out,
                                                  float* __restrict__ csn,
                                                  int nslice) {
    __shared__ float red[NE];
    int j = threadIdx.x;
    float cnt = 0.f;
    for (int s = 0; s < nslice; ++s) cnt += cntp[s * NE + j];   // exact ints
    float ncs = 0.99f * cs_in[j] + 0.01f * cnt;
    out[CS_OFF + j] = ncs;
    red[j] = ncs;
    __syncthreads();
    #pragma unroll
    for (int s = 512; s > 0; s >>= 1) {
        if (j < s) red[j] += red[j + s];
        __syncthreads();
    }
    float n = red[0];
    float cs = ((ncs + 1e-5f) / (n + 0.01024f)) * n;   // (ncs+eps)/(n+NE*eps)*n
    csn[j] = cs;
    if (j == 0) out[LOSS_OFF] = 0.25f * (lossacc[0] * (1.0f / (float)ZTOT));
}

// ---------------- K3: embed_avg EMA + normalized embedding ----------------
__global__ __launch_bounds__(256) void k_embed(const float* __restrict__ ea_in,
                                               const float* __restrict__ epart,
                                               const float* __restrict__ csn,
                                               float* __restrict__ out,
                                               int nslice) {
    int i = blockIdx.x * 256 + threadIdx.x;   // 0..65535
    float es = 0.f;
    for (int s = 0; s < nslice; ++s) es += epart[(size_t)s * (NE * CDIM) + i];
    float nea = 0.99f * ea_in[i] + 0.01f * es;
    out[EA_OFF + i] = nea;
    out[EMB_OFF + i] = nea / csn[i >> 6];
}

extern "C" void kernel_launch(void* const* d_in, const int* in_sizes, int n_in,
                              void* d_out, int out_size, void* d_ws, size_t ws_size,
                              hipStream_t stream) {
    const float* z   = (const float*)d_in[0];
    const float* emb = (const float*)d_in[1];
    const float* cs  = (const float*)d_in[2];
    const float* ea  = (const float*)d_in[3];
    float* out = (float*)d_out;
    float* ws  = (float*)d_ws;

    // pick slice count that fits the workspace (deterministic for fixed ws_size)
    int ns = 8;
    while (ns > 1) {
        size_t need = (size_t)(64 + ns * NE + (size_t)ns * NE * CDIM + 2 * NE) * 4;
        if (need <= ws_size) break;
        ns >>= 1;
    }
    float* ws_loss  = ws;                            // 1 (zeroed)
    float* ws_cntp  = ws + 64;                       // ns*1024
    float* ws_epart = ws_cntp + ns * NE;             // ns*65536
    float* ws_enorm = ws_epart + (size_t)ns * NE * CDIM;  // 1024
    float* ws_csn   = ws_enorm + NE;                 // 1024

    hipMemsetAsync(ws_loss, 0, 256, stream);   // loss accumulator only
    k_enorm<<<256, 256, 0, stream>>>(emb, ws_enorm);
    k_fused4<<<512, 256, 0, stream>>>(z, emb, ws_enorm, out, ws_loss);
    k_scatter<<<ns * 64, 1024, 0, stream>>>(z, out + IDX_OFF, ws_epart, ws_cntp, ns);
    k_cluster<<<1, 1024, 0, stream>>>(cs, ws_cntp, ws_loss, out, ws_csn, ns);
    k_embed<<<256, 256, 0, stream>>>(ea, ws_epart, ws_csn, out, ns);
}

// Round 13
// 200.344 us; speedup vs baseline: 1.1471x; 1.1471x over previous
//
#include <hip/hip_runtime.h>

// Problem constants (fixed shapes from reference)
#define NE    1024
#define CDIM  64
#define BDIM  16
#define HDIM  64
#define WDIM  64
#define NPOS  (BDIM*HDIM*WDIM)          // 65536 positions
#define ZTOT  (BDIM*CDIM*HDIM*WDIM)     // 4194304 elements

// d_out offsets (float elements), concat in reference return order
#define ZQ_OFF   0
#define LOSS_OFF 4194304
#define IDX_OFF  4194305
#define EMB_OFF  4259841
#define CS_OFF   4325377
#define EA_OFF   4326401

// monotone float->uint mapping: a<b  <=>  ordf(a)<ordf(b)
__device__ __forceinline__ unsigned ordf(float x) {
    unsigned b = __float_as_uint(x);
    return (b & 0x80000000u) ? ~b : (b | 0x80000000u);
}

__device__ __forceinline__ unsigned long long umax64(unsigned long long a,
                                                     unsigned long long b) {
    return a > b ? a : b;
}

// ---------------- K0: codebook row norms, pre-scaled by -0.5 ----------------
__global__ __launch_bounds__(256) void k_enorm(const float* __restrict__ emb,
                                               float* __restrict__ en2) {
    int wid  = (blockIdx.x * blockDim.x + threadIdx.x) >> 6;   // row 0..1023
    int lane = threadIdx.x & 63;
    if (wid >= NE) return;
    float v = emb[wid * CDIM + lane];
    float s = v * v;
    #pragma unroll
    for (int off = 32; off > 0; off >>= 1) s += __shfl_xor(s, off);
    if (lane == 0) en2[wid] = -0.5f * s;
}

// ---------------- K1: fused argmin GEMM (16x8 lane tile) + emit ----------------
// R11 structure (z from global L1/L2, E from LDS; 2 b128 per 128 fma ->
// LDS at 25%), with the register budget PINNED: amdgpu_waves_per_eu(2,2)
// => exactly 2 waves/SIMD => 256-VGPR budget, so the ~220-reg live set
// (acc 128 + z-dbuf 32 + E-dbuf 16 + best/bid 32) fits with no AGPR/scratch
// shuffle (R11: allocator kept 128 arch VGPRs -> 23.8MB spill writes).
// Argmin key=(ord(m)<<32)|(1023-j) => max-m-then-min-j == first-argmin.
// Same ascending-c chain per (p,j) as R6/R11 -> identical indices.
__global__ __launch_bounds__(256)
__attribute__((amdgpu_waves_per_eu(2, 2)))
void k_fused3(const float* __restrict__ z,
              const float* __restrict__ emb,
              const float* __restrict__ en2,
              float* __restrict__ out,
              float* __restrict__ lossacc) {
    __shared__ float Et[64 * 256];            // 64 KB [c][jl]
    __shared__ float Nn[256];                 // -0.5||e||^2 for chunk
    __shared__ unsigned long long keyL[128];  // per-position argmin key
    __shared__ float lred[4];

    const int t    = threadIdx.x;
    const int lane = t & 63;
    const int q    = t >> 6;          // wave 0..3 (code sub-range)
    const int lr   = lane >> 3;       // 0..7 position-16-group
    const int lc   = lane & 7;        // 0..7 code octet
    const int blk  = blockIdx.x;      // 0..511

    if (t < 128) keyL[t] = 0ull;

    // lane's z base: 16 consecutive w at row bh = blk*2 + (lr>>2)
    const int bh_l = blk * 2 + (lr >> 2);
    const size_t zlb = (size_t)(bh_l >> 6) * (CDIM * HDIM * WDIM)
                     + (size_t)(bh_l & 63) * WDIM + (lr & 3) * 16;
    const float* __restrict__ zl = z + zlb;
    const int jlbase = q * 64 + lc * 8;

    float acc[16][8];
    float best[16];
    int   bid[16];
    #pragma unroll
    for (int p = 0; p < 16; ++p) { best[p] = -3.4e38f; bid[p] = 0; }

    #define LOADZ(A0, A1, A2, A3, C) do { \
        A0 = *(const float4*)(zl + (size_t)(C) * (HDIM*WDIM)); \
        A1 = *(const float4*)(zl + (size_t)(C) * (HDIM*WDIM) + 4); \
        A2 = *(const float4*)(zl + (size_t)(C) * (HDIM*WDIM) + 8); \
        A3 = *(const float4*)(zl + (size_t)(C) * (HDIM*WDIM) + 12); } while (0)
    #define LOADE(B0, B1, C) do { \
        B0 = *(const float4*)&Et[(C) * 256 + jlbase]; \
        B1 = *(const float4*)&Et[(C) * 256 + jlbase + 4]; } while (0)
    #define FMA8(P, ZV, E0, E1) \
        acc[P][0] = fmaf(ZV, E0.x, acc[P][0]); \
        acc[P][1] = fmaf(ZV, E0.y, acc[P][1]); \
        acc[P][2] = fmaf(ZV, E0.z, acc[P][2]); \
        acc[P][3] = fmaf(ZV, E0.w, acc[P][3]); \
        acc[P][4] = fmaf(ZV, E1.x, acc[P][4]); \
        acc[P][5] = fmaf(ZV, E1.y, acc[P][5]); \
        acc[P][6] = fmaf(ZV, E1.z, acc[P][6]); \
        acc[P][7] = fmaf(ZV, E1.w, acc[P][7]);
    #define COMP(Z0, Z1, Z2, Z3, E0, E1) do { \
        FMA8(0,  Z0.x, E0, E1) FMA8(1,  Z0.y, E0, E1) \
        FMA8(2,  Z0.z, E0, E1) FMA8(3,  Z0.w, E0, E1) \
        FMA8(4,  Z1.x, E0, E1) FMA8(5,  Z1.y, E0, E1) \
        FMA8(6,  Z1.z, E0, E1) FMA8(7,  Z1.w, E0, E1) \
        FMA8(8,  Z2.x, E0, E1) FMA8(9,  Z2.y, E0, E1) \
        FMA8(10, Z2.z, E0, E1) FMA8(11, Z2.w, E0, E1) \
        FMA8(12, Z3.x, E0, E1) FMA8(13, Z3.y, E0, E1) \
        FMA8(14, Z3.z, E0, E1) FMA8(15, Z3.w, E0, E1) } while (0)

    #pragma unroll 1
    for (int ch = 0; ch < 4; ++ch) {
        __syncthreads();   // prior chunk's Et/Nn reads complete

        // ---- stage Et[c][jl] transposed + Nn (thread t = one code row) ----
        {
            const float4* src = (const float4*)(emb + (size_t)(ch * 256 + t) * CDIM);
            #pragma unroll
            for (int k = 0; k < 16; ++k) {
                float4 v = src[k];
                Et[(k * 4 + 0) * 256 + t] = v.x;
                Et[(k * 4 + 1) * 256 + t] = v.y;
                Et[(k * 4 + 2) * 256 + t] = v.z;
                Et[(k * 4 + 3) * 256 + t] = v.w;
            }
            Nn[t] = en2[ch * 256 + t];
        }
        __syncthreads();

        #pragma unroll
        for (int p = 0; p < 16; ++p)
            #pragma unroll
            for (int j = 0; j < 8; ++j) acc[p][j] = 0.f;

        float4 zA0, zA1, zA2, zA3, zB0, zB1, zB2, zB3;
        float4 eA0, eA1, eB0, eB1;
        LOADZ(zA0, zA1, zA2, zA3, 0);
        LOADE(eA0, eA1, 0);
        #pragma unroll 1
        for (int c = 0; c < 64; c += 2) {
            LOADZ(zB0, zB1, zB2, zB3, c + 1);
            LOADE(eB0, eB1, c + 1);
            COMP(zA0, zA1, zA2, zA3, eA0, eA1);
            if (c + 2 < 64) {
                LOADZ(zA0, zA1, zA2, zA3, c + 2);
                LOADE(eA0, eA1, c + 2);
            }
            COMP(zB0, zB1, zB2, zB3, eB0, eB1);
        }

        // ---- fold argmin for this chunk ----
        float4 n0 = *(const float4*)&Nn[jlbase];
        float4 n1 = *(const float4*)&Nn[jlbase + 4];
        const int jg0 = ch * 256 + jlbase;
        #pragma unroll
        for (int p = 0; p < 16; ++p) {
            #define TRY(J, NV) { float m = acc[p][J] + NV; \
                if (m > best[p]) { best[p] = m; bid[p] = jg0 + J; } }
            TRY(0, n0.x) TRY(1, n0.y) TRY(2, n0.z) TRY(3, n0.w)
            TRY(4, n1.x) TRY(5, n1.y) TRY(6, n1.z) TRY(7, n1.w)
            #undef TRY
        }
    }
    #undef LOADZ
    #undef LOADE
    #undef FMA8
    #undef COMP

    // ---- merge across the 8 lc-lanes, then across waves via LDS atomicMax ----
    #pragma unroll
    for (int p = 0; p < 16; ++p) {
        unsigned long long key =
            ((unsigned long long)ordf(best[p]) << 32) | (unsigned)(1023 - bid[p]);
        key = umax64(key, __shfl_xor(key, 1));
        key = umax64(key, __shfl_xor(key, 2));
        key = umax64(key, __shfl_xor(key, 4));
        if (lc == 0) atomicMax(&keyL[lr * 16 + p], key);
    }
    __syncthreads();

    // ---- emit: idx, z_q (straight-through), loss ----
    {
        const int pl   = t & 127;          // position in block
        const int half = t >> 7;           // c-half 0/1
        const int bh   = blk * 2 + (pl >> 6);
        const int w    = pl & 63;
        const size_t zb0 = (size_t)(bh >> 6) * (CDIM * HDIM * WDIM)
                         + (size_t)(bh & 63) * WDIM + w;
        const int bx = 1023 - (int)(unsigned)(keyL[pl] & 0xFFFFFFFFull);

        if (half == 0) out[IDX_OFF + blk * 128 + pl] = (float)bx;

        const float4* ev = (const float4*)(emb + (size_t)bx * CDIM);
        float lsum = 0.f;
        #pragma unroll
        for (int k4 = 0; k4 < 8; ++k4) {
            float4 e4 = ev[half * 8 + k4];
            #pragma unroll
            for (int k = 0; k < 4; ++k) {
                const int c = half * 32 + k4 * 4 + k;
                float zv = z[zb0 + (size_t)c * (HDIM * WDIM)];
                float evv = (k == 0) ? e4.x : (k == 1) ? e4.y
                          : (k == 2) ? e4.z : e4.w;
                float df = evv - zv;
                out[ZQ_OFF + zb0 + (size_t)c * (HDIM * WDIM)] = zv + df;
                lsum = fmaf(df, df, lsum);
            }
        }

        #pragma unroll
        for (int off = 32; off > 0; off >>= 1) lsum += __shfl_xor(lsum, off);
        if ((t & 63) == 0) lred[t >> 6] = lsum;
        __syncthreads();
        if (t == 0)
            atomicAdd(lossacc, (lred[0] + lred[1]) + (lred[2] + lred[3]));
    }
}

// ---------------- K1b: esum/counts partials, channel x position-slice ----------------
__global__ __launch_bounds__(1024) void k_scatter(const float* __restrict__ z,
                                                  const float* __restrict__ idxf,
                                                  float* __restrict__ epart,
                                                  float* __restrict__ cntp,
                                                  int nslice) {
    __shared__ float accJ[NE];
    __shared__ float cntJ[NE];

    const int t = threadIdx.x;
    const int c = blockIdx.x & 63;
    const int s = blockIdx.x >> 6;
    accJ[t] = 0.f;
    cntJ[t] = 0.f;
    __syncthreads();

    const bool do_cnt = (c == 0);
    const int per = NPOS / nslice;
    const int p0  = s * per;
    for (int k = 0; k < per; k += 1024) {
        const int p = p0 + k + t;
        const int j = (int)idxf[p];                    // exact for 0..1023
        const int b = p >> 12, hw = p & 4095;
        const float zv = z[(size_t)b * (CDIM * HDIM * WDIM) + c * (HDIM * WDIM) + hw];
        atomicAdd(&accJ[j], zv);                       // ds_add_f32
        if (do_cnt) atomicAdd(&cntJ[j], 1.0f);
    }
    __syncthreads();

    epart[(size_t)s * (NE * CDIM) + t * CDIM + c] = accJ[t];
    if (do_cnt) cntp[s * NE + t] = cntJ[t];
}

// ---------------- K2: cluster-size EMA + n-sum + loss ----------------
__global__ __launch_bounds__(1024) void k_cluster(const float* __restrict__ cs_in,
                                                  const float* __restrict__ cntp,
                                                  const float* __restrict__ lossacc,
                                                  float* __restrict__ out,
                                                  float* __restrict__ csn,
                                                  int nslice) {
    __shared__ float red[NE];
    int j = threadIdx.x;
    float cnt = 0.f;
    for (int s = 0; s < nslice; ++s) cnt += cntp[s * NE + j];   // exact ints
    float ncs = 0.99f * cs_in[j] + 0.01f * cnt;
    out[CS_OFF + j] = ncs;
    red[j] = ncs;
    __syncthreads();
    #pragma unroll
    for (int s = 512; s > 0; s >>= 1) {
        if (j < s) red[j] += red[j + s];
        __syncthreads();
    }
    float n = red[0];
    float cs = ((ncs + 1e-5f) / (n + 0.01024f)) * n;   // (ncs+eps)/(n+NE*eps)*n
    csn[j] = cs;
    if (j == 0) out[LOSS_OFF] = 0.25f * (lossacc[0] * (1.0f / (float)ZTOT));
}

// ---------------- K3: embed_avg EMA + normalized embedding ----------------
__global__ __launch_bounds__(256) void k_embed(const float* __restrict__ ea_in,
                                               const float* __restrict__ epart,
                                               const float* __restrict__ csn,
                                               float* __restrict__ out,
                                               int nslice) {
    int i = blockIdx.x * 256 + threadIdx.x;   // 0..65535
    float es = 0.f;
    for (int s = 0; s < nslice; ++s) es += epart[(size_t)s * (NE * CDIM) + i];
    float nea = 0.99f * ea_in[i] + 0.01f * es;
    out[EA_OFF + i] = nea;
    out[EMB_OFF + i] = nea / csn[i >> 6];
}

extern "C" void kernel_launch(void* const* d_in, const int* in_sizes, int n_in,
                              void* d_out, int out_size, void* d_ws, size_t ws_size,
                              hipStream_t stream) {
    const float* z   = (const float*)d_in[0];
    const float* emb = (const float*)d_in[1];
    const float* cs  = (const float*)d_in[2];
    const float* ea  = (const float*)d_in[3];
    float* out = (float*)d_out;
    float* ws  = (float*)d_ws;

    // pick slice count that fits the workspace (deterministic for fixed ws_size)
    int ns = 8;
    while (ns > 1) {
        size_t need = (size_t)(64 + ns * NE + (size_t)ns * NE * CDIM + 2 * NE) * 4;
        if (need <= ws_size) break;
        ns >>= 1;
    }
    float* ws_loss  = ws;                            // 1 (zeroed)
    float* ws_cntp  = ws + 64;                       // ns*1024
    float* ws_epart = ws_cntp + ns * NE;             // ns*65536
    float* ws_enorm = ws_epart + (size_t)ns * NE * CDIM;  // 1024
    float* ws_csn   = ws_enorm + NE;                 // 1024

    hipMemsetAsync(ws_loss, 0, 256, stream);   // loss accumulator only
    k_enorm<<<256, 256, 0, stream>>>(emb, ws_enorm);
    k_fused3<<<512, 256, 0, stream>>>(z, emb, ws_enorm, out, ws_loss);
    k_scatter<<<ns * 64, 1024, 0, stream>>>(z, out + IDX_OFF, ws_epart, ws_cntp, ns);
    k_cluster<<<1, 1024, 0, stream>>>(cs, ws_cntp, ws_loss, out, ws_csn, ns);
    k_embed<<<256, 256, 0, stream>>>(ea, ws_epart, ws_csn, out, ns);
}